// Round 10
// baseline (218.461 us; speedup 1.0000x reference)
//
#include <hip/hip_runtime.h>
#include <hip/hip_cooperative_groups.h>

namespace cg = cooperative_groups;

#define B 4
#define C 19
#define H 192
#define W 192
#define HW (H * W)
// 40 / ln(2): exp(-40*x) == exp2(-THETA_LOG2E*x)
#define THETA_LOG2E 57.70780163555855f

#define CSEGS 8
#define CSR 24        // rows per segment in the column-scan phase
#define NBLK 228      // = B*C*3 column-phase blocks; 1824 waves for the row phase
#define NTHR 512
#define NWAVES (NBLK * 8)   // 1824
#define NROWS (B * C * H)   // 14592 = NWAVES * 8

// ================= column scan phase =================
// csum[b,c,i,j] = Zc + Sc - f ; DENOM: c==0 blocks also write dcol = Zu + Su - 1
template<bool DENOM>
__device__ __forceinline__ void col_phase(const float* __restrict__ fin,
                                          const float* __restrict__ edge,
                                          float* __restrict__ csum,
                                          float* __restrict__ dcolg,
                                          float* sPf, float* sQf, float* sPb, float* sQb,
                                          int blk, int t) {
    int jt = blk % 3;
    int bc = blk / 3;
    int b = bc / C;
    int c = bc % C;
    int jl = t & 63, seg = t >> 6;
    int j = jt * 64 + jl;
    int i0 = seg * CSR;

    const float* ep = edge + ((size_t)b * H + i0) * W + j;
    const float* fp = fin + ((size_t)bc * H + i0) * W + j;
    float* op = csum + ((size_t)bc * H + i0) * W + j;

    float dr[CSR + 1], fr[CSR];
    #pragma unroll
    for (int r = 0; r < CSR; ++r) {
        dr[r] = exp2f(-THETA_LOG2E * fmaxf(ep[r * W], 0.f));
        fr[r] = fp[r * W];
    }
    dr[CSR] = (seg < CSEGS - 1) ? exp2f(-THETA_LOG2E * fmaxf(ep[CSR * W], 0.f)) : 0.f;

    float Pf = 1.f, Qf = 0.f, Pb = 1.f, Qb = 0.f;
    #pragma unroll
    for (int r = 0; r < CSR; ++r) { Qf = Qf * dr[r] + fr[r]; Pf *= dr[r]; }
    #pragma unroll
    for (int r = CSR - 1; r >= 0; --r) { Qb = Qb * dr[r + 1] + fr[r]; Pb *= dr[r + 1]; }
    sPf[seg * 64 + jl] = Pf; sQf[seg * 64 + jl] = Qf;
    sPb[seg * 64 + jl] = Pb; sQb[seg * 64 + jl] = Qb;
    __syncthreads();
    if (seg == 0) {          // inclusive prefix transforms
        float P = sPf[jl], Q = sQf[jl];
        for (int s2 = 1; s2 < CSEGS; ++s2) {
            float Pc = sPf[s2 * 64 + jl], Qc = sQf[s2 * 64 + jl];
            Q = Q * Pc + Qc; P = P * Pc;
            sPf[s2 * 64 + jl] = P; sQf[s2 * 64 + jl] = Q;
        }
    } else if (seg == 1) {   // inclusive suffix transforms
        float P = sPb[(CSEGS - 1) * 64 + jl], Q = sQb[(CSEGS - 1) * 64 + jl];
        for (int s2 = CSEGS - 2; s2 >= 0; --s2) {
            float Pc = sPb[s2 * 64 + jl], Qc = sQb[s2 * 64 + jl];
            Q = Q * Pc + Qc; P = P * Pc;
            sPb[s2 * 64 + jl] = P; sQb[s2 * 64 + jl] = Q;
        }
    }
    __syncthreads();
    float z = (seg > 0) ? sQf[(seg - 1) * 64 + jl] : 0.f;
    float s = (seg < CSEGS - 1) ? sQb[(seg + 1) * 64 + jl] : 0.f;
    float zarr[CSR];
    #pragma unroll
    for (int r = 0; r < CSR; ++r) { z = z * dr[r] + fr[r]; zarr[r] = z; }
    #pragma unroll
    for (int r = CSR - 1; r >= 0; --r) {
        s = s * dr[r + 1] + fr[r];
        op[r * W] = zarr[r] + s - fr[r];     // diagonal counted once
    }

    if (DENOM && c == 0) {
        float Pf2 = 1.f, Qf2 = 0.f, Pb2 = 1.f, Qb2 = 0.f;
        #pragma unroll
        for (int r = 0; r < CSR; ++r) { Qf2 = Qf2 * dr[r] + 1.f; Pf2 *= dr[r]; }
        #pragma unroll
        for (int r = CSR - 1; r >= 0; --r) { Qb2 = Qb2 * dr[r + 1] + 1.f; Pb2 *= dr[r + 1]; }
        __syncthreads();
        sPf[seg * 64 + jl] = Pf2; sQf[seg * 64 + jl] = Qf2;
        sPb[seg * 64 + jl] = Pb2; sQb[seg * 64 + jl] = Qb2;
        __syncthreads();
        if (seg == 0) {
            float P = sPf[jl], Q = sQf[jl];
            for (int s2 = 1; s2 < CSEGS; ++s2) {
                float Pc = sPf[s2 * 64 + jl], Qc = sQf[s2 * 64 + jl];
                Q = Q * Pc + Qc; P = P * Pc;
                sPf[s2 * 64 + jl] = P; sQf[s2 * 64 + jl] = Q;
            }
        } else if (seg == 1) {
            float P = sPb[(CSEGS - 1) * 64 + jl], Q = sQb[(CSEGS - 1) * 64 + jl];
            for (int s2 = CSEGS - 2; s2 >= 0; --s2) {
                float Pc = sPb[s2 * 64 + jl], Qc = sQb[s2 * 64 + jl];
                Q = Q * Pc + Qc; P = P * Pc;
                sPb[s2 * 64 + jl] = P; sQb[s2 * 64 + jl] = Q;
            }
        }
        __syncthreads();
        float zu = (seg > 0) ? sQf[(seg - 1) * 64 + jl] : 0.f;
        float su = (seg < CSEGS - 1) ? sQb[(seg + 1) * 64 + jl] : 0.f;
        float* dop = dcolg + ((size_t)b * H + i0) * W + j;
        #pragma unroll
        for (int r = 0; r < CSR; ++r) { zu = zu * dr[r] + 1.f; zarr[r] = zu; }
        #pragma unroll
        for (int r = CSR - 1; r >= 0; --r) {
            su = su * dr[r + 1] + 1.f;
            dop[r * W] = zarr[r] + su - 1.f;
        }
    }
}

// ================= row scan + combine, one row =================
template<bool FIRST>
__device__ __forceinline__ void row_one(int rr, int lane,
                                        const float* fin, float* fout,
                                        const float* __restrict__ edge,
                                        const float* __restrict__ csum,
                                        const float* __restrict__ dcolg,
                                        float* __restrict__ rDg) {
    const int i = rr % H;
    const int c = (rr / H) % C;
    const int b = rr / (H * C);
    const size_t rb = ((size_t)(b * C + c) * H + i) * W;
    const int db = (b * H + i) * W;
    const int s0 = 3 * lane;

    float e0 = edge[db + s0], e1 = edge[db + s0 + 1], e2 = edge[db + s0 + 2];
    float d0 = exp2f(-THETA_LOG2E * fmaxf(e0, 0.f));
    float d1 = exp2f(-THETA_LOG2E * fmaxf(e1, 0.f));
    float d2 = exp2f(-THETA_LOG2E * fmaxf(e2, 0.f));
    float d3 = 0.f;
    if (lane < 63) {
        float e3 = edge[db + s0 + 3];
        d3 = exp2f(-THETA_LOG2E * fmaxf(e3, 0.f));
    }
    float f0 = fin[rb + s0], f1 = fin[rb + s0 + 1], f2 = fin[rb + s0 + 2];

    // forward scan
    float P = d0 * d1 * d2;
    float Q = (f0 * d1 + f1) * d2 + f2;
    #pragma unroll
    for (int off = 1; off < 64; off <<= 1) {
        float Pp = __shfl_up(P, off);
        float Qp = __shfl_up(Q, off);
        if (lane >= off) { Q = Qp * P + Q; P = Pp * P; }
    }
    float zin = __shfl_up(Q, 1);
    if (lane == 0) zin = 0.f;
    float zA = zin * d0 + f0;
    float zB = zA * d1 + f1;
    float zC = zB * d2 + f2;

    // backward scan
    float Pb = d3 * d2 * d1;
    float Qb = (f2 * d2 + f1) * d1 + f0;
    #pragma unroll
    for (int off = 1; off < 64; off <<= 1) {
        float Pp = __shfl_down(Pb, off);
        float Qp = __shfl_down(Qb, off);
        if (lane < 64 - off) { Qb = Qp * Pb + Qb; Pb = Pp * Pb; }
    }
    float sin_ = __shfl_down(Qb, 1);
    if (lane == 63) sin_ = 0.f;
    float sC = sin_ * d3 + f2;
    float sB = sC * d2 + f1;
    float sA = sB * d1 + f0;

    float rd0, rd1, rd2;
    if (FIRST) {
        float Pu = d0 * d1 * d2;
        float Qu = d1 * d2 + d2 + 1.f;
        #pragma unroll
        for (int off = 1; off < 64; off <<= 1) {
            float Pp = __shfl_up(Pu, off);
            float Qp = __shfl_up(Qu, off);
            if (lane >= off) { Qu = Qp * Pu + Qu; Pu = Pp * Pu; }
        }
        float zuin = __shfl_up(Qu, 1);
        if (lane == 0) zuin = 0.f;
        float zuA = zuin * d0 + 1.f;
        float zuB = zuA * d1 + 1.f;
        float zuC = zuB * d2 + 1.f;

        float Pub = d3 * d2 * d1;
        float Qub = d2 * d1 + d1 + 1.f;
        #pragma unroll
        for (int off = 1; off < 64; off <<= 1) {
            float Pp = __shfl_down(Pub, off);
            float Qp = __shfl_down(Qub, off);
            if (lane < 64 - off) { Qub = Qp * Pub + Qub; Pub = Pp * Pub; }
        }
        float suin = __shfl_down(Qub, 1);
        if (lane == 63) suin = 0.f;
        float suC = suin * d3 + 1.f;
        float suB = suC * d2 + 1.f;
        float suA = suB * d1 + 1.f;

        rd0 = 1.f / (dcolg[db + s0]     + zuA + suA - 2.f);
        rd1 = 1.f / (dcolg[db + s0 + 1] + zuB + suB - 2.f);
        rd2 = 1.f / (dcolg[db + s0 + 2] + zuC + suC - 2.f);
        if (c == 0) {
            rDg[db + s0]     = rd0;
            rDg[db + s0 + 1] = rd1;
            rDg[db + s0 + 2] = rd2;
        }
    } else {
        rd0 = rDg[db + s0];
        rd1 = rDg[db + s0 + 1];
        rd2 = rDg[db + s0 + 2];
    }

    float cs0 = csum[rb + s0], cs1 = csum[rb + s0 + 1], cs2 = csum[rb + s0 + 2];
    fout[rb + s0]     = (cs0 + zA + sA - 2.f * f0) * rd0;
    fout[rb + s0 + 1] = (cs1 + zB + sB - 2.f * f1) * rd1;
    fout[rb + s0 + 2] = (cs2 + zC + sC - 2.f * f2) * rd2;
}

template<bool FIRST>
__device__ __forceinline__ void row_phase(const float* fin, float* fout,
                                          const float* __restrict__ edge,
                                          const float* __restrict__ csum,
                                          const float* __restrict__ dcolg,
                                          float* __restrict__ rDg,
                                          int blk, int t) {
    const int wave = t >> 6, lane = t & 63;
    const int gw = blk * 8 + wave;     // 0..1823
    for (int k = 0; k < 8; ++k)
        row_one<FIRST>(gw + k * NWAVES, lane, fin, fout, edge, csum, dcolg, rDg);
}

// ================= cooperative all-phases kernel =================
__global__ __launch_bounds__(NTHR, 2) void k_coop(const float* __restrict__ mask,
                                                  const float* __restrict__ edge,
                                                  float* __restrict__ outg,
                                                  float* __restrict__ csum,
                                                  float* __restrict__ dcolg,
                                                  float* __restrict__ rDg) {
    __shared__ float sPf[CSEGS * 64], sQf[CSEGS * 64], sPb[CSEGS * 64], sQb[CSEGS * 64];
    cg::grid_group grid = cg::this_grid();
    const int t = threadIdx.x, blk = blockIdx.x;

    col_phase<true>(mask, edge, csum, dcolg, sPf, sQf, sPb, sQb, blk, t);
    grid.sync();
    row_phase<true>(mask, outg, edge, csum, dcolg, rDg, blk, t);
    grid.sync();
    col_phase<false>(outg, edge, csum, nullptr, sPf, sQf, sPb, sQb, blk, t);
    grid.sync();
    row_phase<false>(outg, outg, edge, csum, nullptr, rDg, blk, t);
    grid.sync();
    col_phase<false>(outg, edge, csum, nullptr, sPf, sQf, sPb, sQb, blk, t);
    grid.sync();
    row_phase<false>(outg, outg, edge, csum, nullptr, rDg, blk, t);
}

// ================= fallback kernels (R9 path, used only if cooperative launch fails) =================
template<bool DENOM>
__global__ __launch_bounds__(512) void k_col(const float* __restrict__ fin,
                                             const float* __restrict__ edge,
                                             float* __restrict__ csum,
                                             float* __restrict__ dcolg) {
    __shared__ float sPf[CSEGS * 64], sQf[CSEGS * 64], sPb[CSEGS * 64], sQb[CSEGS * 64];
    col_phase<DENOM>(fin, edge, csum, dcolg, sPf, sQf, sPb, sQb, blockIdx.x, threadIdx.x);
}

template<bool FIRST>
__global__ __launch_bounds__(256) void k_row(const float* fin, float* fout,
                                             const float* __restrict__ edge,
                                             const float* __restrict__ csum,
                                             const float* __restrict__ dcolg,
                                             float* __restrict__ rDg) {
    int wid = (blockIdx.x * 256 + threadIdx.x) >> 6;   // one row per wave
    int lane = threadIdx.x & 63;
    row_one<FIRST>(wid, lane, fin, fout, edge, csum, dcolg, rDg);
}

extern "C" void kernel_launch(void* const* d_in, const int* in_sizes, int n_in,
                              void* d_out, int out_size, void* d_ws, size_t ws_size,
                              hipStream_t stream) {
    const float* mask = (const float*)d_in[0];
    const float* edge = (const float*)d_in[1];
    float* out = (float*)d_out;

    float* csum = (float*)d_ws;                 // [B*C,H,W]  11.3 MB
    float* dcol = csum + (size_t)B * C * HW;    // [B,H,W]
    float* rDg  = dcol + B * HW;                // [B,H,W]

    void* args[] = {(void*)&mask, (void*)&edge, (void*)&out,
                    (void*)&csum, (void*)&dcol, (void*)&rDg};
    hipError_t err = hipLaunchCooperativeKernel((const void*)k_coop, dim3(NBLK), dim3(NTHR),
                                                args, 0, stream);
    if (err != hipSuccess) {
        (void)hipGetLastError();   // clear sticky error; fall back to the 6-kernel path
        const int colgrid = B * C * 3;          // 228 x 512
        const int rowgrid = (B * C * H) / 4;    // 3648 x 256
        k_col<true><<<colgrid, 512, 0, stream>>>(mask, edge, csum, dcol);
        k_row<true><<<rowgrid, 256, 0, stream>>>(mask, out, edge, csum, dcol, rDg);
        k_col<false><<<colgrid, 512, 0, stream>>>(out, edge, csum, nullptr);
        k_row<false><<<rowgrid, 256, 0, stream>>>(out, out, edge, csum, nullptr, rDg);
        k_col<false><<<colgrid, 512, 0, stream>>>(out, edge, csum, nullptr);
        k_row<false><<<rowgrid, 256, 0, stream>>>(out, out, edge, csum, nullptr, rDg);
    }
}

// Round 11
// 50.907 us; speedup vs baseline: 4.2914x; 4.2914x over previous
//
#include <hip/hip_runtime.h>

#define B 4
#define C 19
#define H 192
#define W 192
#define HW (H * W)
// 40 / ln(2): exp(-40*x) == exp2(-THETA_LOG2E*x)
#define THETA_LOG2E 57.70780163555855f

#define CSEGS 8
#define CSR 24            // rows per segment (column role)
#define NCOLB (B * C * 3) // 228 column-role blocks
#define NROWB (B * C * H / 8)  // 1824 row-role blocks (8 waves x 1 row)
#define NTHR 512

// bf16 helpers (RNE)
__device__ __forceinline__ unsigned short f2b(float x) {
    unsigned u = __float_as_uint(x);
    u = (u + 0x7FFFu + ((u >> 16) & 1u)) >> 16;
    return (unsigned short)u;
}
__device__ __forceinline__ float b2f(unsigned short h) {
    return __uint_as_float(((unsigned)h) << 16);
}

// ================= per-iteration kernel: col role + row role in one grid =================
// col role  : cs_k[b,c,i,j] = Zc + Sc - f_k           (bf16 out)
// row role  : rs_k[b,c,i,j] = Zr + Sr - 2 f_k         (bf16 out)
// f_k = mask (FIRST) or (cs_{k-1} + rs_{k-1}) * rD, rD = 1/(dcol + drow - 1), folded on the fly.
// FIRST also computes dcol (unit col scan, col role c==0) and drow (unit row scan, row role c==0).
template<bool FIRST>
__global__ __launch_bounds__(NTHR) void k_iter(const float* __restrict__ mask,
                                               const float* __restrict__ edge,
                                               const unsigned short* __restrict__ csin,
                                               const unsigned short* __restrict__ rsin,
                                               unsigned short* __restrict__ csout,
                                               unsigned short* __restrict__ rsout,
                                               float* __restrict__ dcol,
                                               float* __restrict__ drow) {
    const int t = threadIdx.x;
    if (blockIdx.x < NCOLB) {
        // ---------------- column role ----------------
        __shared__ float sPf[CSEGS * 64], sQf[CSEGS * 64], sPb[CSEGS * 64], sQb[CSEGS * 64];
        int blk = blockIdx.x;
        int jt = blk % 3, bc = blk / 3, b = bc / C, c = bc % C;
        int jl = t & 63, seg = t >> 6;
        int j = jt * 64 + jl, i0 = seg * CSR;

        const float* ep = edge + ((size_t)b * H + i0) * W + j;
        const size_t fb = ((size_t)bc * H + i0) * W + j;
        const size_t db = ((size_t)b * H + i0) * W + j;

        float dr[CSR + 1], fr[CSR];
        #pragma unroll
        for (int r = 0; r < CSR; ++r) dr[r] = exp2f(-THETA_LOG2E * fmaxf(ep[r * W], 0.f));
        dr[CSR] = (seg < CSEGS - 1) ? exp2f(-THETA_LOG2E * fmaxf(ep[CSR * W], 0.f)) : 0.f;

        if (FIRST) {
            #pragma unroll
            for (int r = 0; r < CSR; ++r) fr[r] = mask[fb + r * W];
        } else {
            #pragma unroll
            for (int r = 0; r < CSR; ++r) {
                float cs = b2f(csin[fb + r * W]);
                float rs = b2f(rsin[fb + r * W]);
                float rd = 1.f / (dcol[db + r * W] + drow[db + r * W] - 1.f);
                fr[r] = (cs + rs) * rd;
            }
        }

        float Pf = 1.f, Qf = 0.f, Pb = 1.f, Qb = 0.f;
        #pragma unroll
        for (int r = 0; r < CSR; ++r) { Qf = Qf * dr[r] + fr[r]; Pf *= dr[r]; }
        #pragma unroll
        for (int r = CSR - 1; r >= 0; --r) { Qb = Qb * dr[r + 1] + fr[r]; Pb *= dr[r + 1]; }
        sPf[seg * 64 + jl] = Pf; sQf[seg * 64 + jl] = Qf;
        sPb[seg * 64 + jl] = Pb; sQb[seg * 64 + jl] = Qb;
        __syncthreads();
        if (seg == 0) {
            float P = sPf[jl], Q = sQf[jl];
            for (int s2 = 1; s2 < CSEGS; ++s2) {
                float Pc = sPf[s2 * 64 + jl], Qc = sQf[s2 * 64 + jl];
                Q = Q * Pc + Qc; P = P * Pc;
                sPf[s2 * 64 + jl] = P; sQf[s2 * 64 + jl] = Q;
            }
        } else if (seg == 1) {
            float P = sPb[(CSEGS - 1) * 64 + jl], Q = sQb[(CSEGS - 1) * 64 + jl];
            for (int s2 = CSEGS - 2; s2 >= 0; --s2) {
                float Pc = sPb[s2 * 64 + jl], Qc = sQb[s2 * 64 + jl];
                Q = Q * Pc + Qc; P = P * Pc;
                sPb[s2 * 64 + jl] = P; sQb[s2 * 64 + jl] = Q;
            }
        }
        __syncthreads();
        float z = (seg > 0) ? sQf[(seg - 1) * 64 + jl] : 0.f;
        float s = (seg < CSEGS - 1) ? sQb[(seg + 1) * 64 + jl] : 0.f;
        float zarr[CSR];
        #pragma unroll
        for (int r = 0; r < CSR; ++r) { z = z * dr[r] + fr[r]; zarr[r] = z; }
        #pragma unroll
        for (int r = CSR - 1; r >= 0; --r) {
            s = s * dr[r + 1] + fr[r];
            csout[fb + r * W] = f2b(zarr[r] + s - fr[r]);   // diagonal counted once
        }

        if (FIRST && c == 0) {
            // unit-f column scan -> dcol = Zu + Su - 1 (fp32)
            float Pf2 = 1.f, Qf2 = 0.f, Pb2 = 1.f, Qb2 = 0.f;
            #pragma unroll
            for (int r = 0; r < CSR; ++r) { Qf2 = Qf2 * dr[r] + 1.f; Pf2 *= dr[r]; }
            #pragma unroll
            for (int r = CSR - 1; r >= 0; --r) { Qb2 = Qb2 * dr[r + 1] + 1.f; Pb2 *= dr[r + 1]; }
            __syncthreads();
            sPf[seg * 64 + jl] = Pf2; sQf[seg * 64 + jl] = Qf2;
            sPb[seg * 64 + jl] = Pb2; sQb[seg * 64 + jl] = Qb2;
            __syncthreads();
            if (seg == 0) {
                float P = sPf[jl], Q = sQf[jl];
                for (int s2 = 1; s2 < CSEGS; ++s2) {
                    float Pc = sPf[s2 * 64 + jl], Qc = sQf[s2 * 64 + jl];
                    Q = Q * Pc + Qc; P = P * Pc;
                    sPf[s2 * 64 + jl] = P; sQf[s2 * 64 + jl] = Q;
                }
            } else if (seg == 1) {
                float P = sPb[(CSEGS - 1) * 64 + jl], Q = sQb[(CSEGS - 1) * 64 + jl];
                for (int s2 = CSEGS - 2; s2 >= 0; --s2) {
                    float Pc = sPb[s2 * 64 + jl], Qc = sQb[s2 * 64 + jl];
                    Q = Q * Pc + Qc; P = P * Pc;
                    sPb[s2 * 64 + jl] = P; sQb[s2 * 64 + jl] = Q;
                }
            }
            __syncthreads();
            float zu = (seg > 0) ? sQf[(seg - 1) * 64 + jl] : 0.f;
            float su = (seg < CSEGS - 1) ? sQb[(seg + 1) * 64 + jl] : 0.f;
            #pragma unroll
            for (int r = 0; r < CSR; ++r) { zu = zu * dr[r] + 1.f; zarr[r] = zu; }
            #pragma unroll
            for (int r = CSR - 1; r >= 0; --r) {
                su = su * dr[r + 1] + 1.f;
                dcol[db + r * W] = zarr[r] + su - 1.f;
            }
        }
    } else {
        // ---------------- row role: one row per wave ----------------
        int rblk = blockIdx.x - NCOLB;
        int wave = t >> 6, lane = t & 63;
        int rr = rblk * 8 + wave;              // 0 .. B*C*H-1
        int i = rr % H;
        int c = (rr / H) % C;
        int b = rr / (H * C);
        const size_t rb = ((size_t)(b * C + c) * H + i) * W;
        const int db = (b * H + i) * W;
        const int s0 = 3 * lane;

        float e0 = edge[db + s0], e1 = edge[db + s0 + 1], e2 = edge[db + s0 + 2];
        float d0 = exp2f(-THETA_LOG2E * fmaxf(e0, 0.f));
        float d1 = exp2f(-THETA_LOG2E * fmaxf(e1, 0.f));
        float d2 = exp2f(-THETA_LOG2E * fmaxf(e2, 0.f));
        float d3 = 0.f;
        if (lane < 63) {
            float e3 = edge[db + s0 + 3];
            d3 = exp2f(-THETA_LOG2E * fmaxf(e3, 0.f));
        }

        float f0, f1, f2;
        if (FIRST) {
            f0 = mask[rb + s0]; f1 = mask[rb + s0 + 1]; f2 = mask[rb + s0 + 2];
        } else {
            float rd0 = 1.f / (dcol[db + s0]     + drow[db + s0]     - 1.f);
            float rd1 = 1.f / (dcol[db + s0 + 1] + drow[db + s0 + 1] - 1.f);
            float rd2 = 1.f / (dcol[db + s0 + 2] + drow[db + s0 + 2] - 1.f);
            f0 = (b2f(csin[rb + s0])     + b2f(rsin[rb + s0]))     * rd0;
            f1 = (b2f(csin[rb + s0 + 1]) + b2f(rsin[rb + s0 + 1])) * rd1;
            f2 = (b2f(csin[rb + s0 + 2]) + b2f(rsin[rb + s0 + 2])) * rd2;
        }

        // forward scan: Z[s] = d[s]*Z[s-1] + f[s]
        float P = d0 * d1 * d2;
        float Q = (f0 * d1 + f1) * d2 + f2;
        #pragma unroll
        for (int off = 1; off < 64; off <<= 1) {
            float Pp = __shfl_up(P, off);
            float Qp = __shfl_up(Q, off);
            if (lane >= off) { Q = Qp * P + Q; P = Pp * P; }
        }
        float zin = __shfl_up(Q, 1);
        if (lane == 0) zin = 0.f;
        float zA = zin * d0 + f0;
        float zB = zA * d1 + f1;
        float zC = zB * d2 + f2;

        // backward scan: Sf[s] = d[s+1]*Sf[s+1] + f[s]
        float Pb = d3 * d2 * d1;
        float Qb = (f2 * d2 + f1) * d1 + f0;
        #pragma unroll
        for (int off = 1; off < 64; off <<= 1) {
            float Pp = __shfl_down(Pb, off);
            float Qp = __shfl_down(Qb, off);
            if (lane < 64 - off) { Qb = Qp * Pb + Qb; Pb = Pp * Pb; }
        }
        float sin_ = __shfl_down(Qb, 1);
        if (lane == 63) sin_ = 0.f;
        float sC = sin_ * d3 + f2;
        float sB = sC * d2 + f1;
        float sA = sB * d1 + f0;

        rsout[rb + s0]     = f2b(zA + sA - 2.f * f0);
        rsout[rb + s0 + 1] = f2b(zB + sB - 2.f * f1);
        rsout[rb + s0 + 2] = f2b(zC + sC - 2.f * f2);

        if (FIRST && c == 0) {
            // unit-f row scan -> drow = Zu + Su - 1 (fp32)
            float Pu = d0 * d1 * d2;
            float Qu = d1 * d2 + d2 + 1.f;
            #pragma unroll
            for (int off = 1; off < 64; off <<= 1) {
                float Pp = __shfl_up(Pu, off);
                float Qp = __shfl_up(Qu, off);
                if (lane >= off) { Qu = Qp * Pu + Qu; Pu = Pp * Pu; }
            }
            float zuin = __shfl_up(Qu, 1);
            if (lane == 0) zuin = 0.f;
            float zuA = zuin * d0 + 1.f;
            float zuB = zuA * d1 + 1.f;
            float zuC = zuB * d2 + 1.f;

            float Pub = d3 * d2 * d1;
            float Qub = d2 * d1 + d1 + 1.f;
            #pragma unroll
            for (int off = 1; off < 64; off <<= 1) {
                float Pp = __shfl_down(Pub, off);
                float Qp = __shfl_down(Qub, off);
                if (lane < 64 - off) { Qub = Qp * Pub + Qub; Pub = Pp * Pub; }
            }
            float suin = __shfl_down(Qub, 1);
            if (lane == 63) suin = 0.f;
            float suC = suin * d3 + 1.f;
            float suB = suC * d2 + 1.f;
            float suA = suB * d1 + 1.f;

            drow[db + s0]     = zuA + suA - 1.f;
            drow[db + s0 + 1] = zuB + suB - 1.f;
            drow[db + s0 + 2] = zuC + suC - 1.f;
        }
    }
}

// ================= final combine: out = (cs + rs) / (dcol + drow - 1) =================
__global__ __launch_bounds__(256) void k_comb(const unsigned short* __restrict__ cs,
                                              const unsigned short* __restrict__ rs,
                                              const float* __restrict__ dcol,
                                              const float* __restrict__ drow,
                                              float* __restrict__ out) {
    int idx4 = (blockIdx.x * 256 + threadIdx.x) * 4;    // B*C*HW / 4 threads
    int bc = idx4 / HW;
    int rem = idx4 - bc * HW;
    int b = bc / C;
    size_t db = (size_t)b * HW + rem;
    uint2 csu = *(const uint2*)(cs + idx4);
    uint2 rsu = *(const uint2*)(rs + idx4);
    float4 dc = *(const float4*)(dcol + db);
    float4 dw = *(const float4*)(drow + db);
    float4 o;
    o.x = (b2f((unsigned short)(csu.x & 0xffff)) + b2f((unsigned short)(rsu.x & 0xffff))) / (dc.x + dw.x - 1.f);
    o.y = (b2f((unsigned short)(csu.x >> 16))    + b2f((unsigned short)(rsu.x >> 16)))    / (dc.y + dw.y - 1.f);
    o.z = (b2f((unsigned short)(csu.y & 0xffff)) + b2f((unsigned short)(rsu.y & 0xffff))) / (dc.z + dw.z - 1.f);
    o.w = (b2f((unsigned short)(csu.y >> 16))    + b2f((unsigned short)(rsu.y >> 16)))    / (dc.w + dw.w - 1.f);
    *(float4*)(out + idx4) = o;
}

extern "C" void kernel_launch(void* const* d_in, const int* in_sizes, int n_in,
                              void* d_out, int out_size, void* d_ws, size_t ws_size,
                              hipStream_t stream) {
    const float* mask = (const float*)d_in[0];
    const float* edge = (const float*)d_in[1];
    float* out = (float*)d_out;

    float* dcol = (float*)d_ws;                         // [B,H,W] fp32
    float* drow = dcol + (size_t)B * HW;                // [B,H,W] fp32
    unsigned short* csA = (unsigned short*)(drow + (size_t)B * HW);
    unsigned short* rsA = csA + (size_t)B * C * HW;     // bf16 [B*C,H,W] each
    unsigned short* csB = rsA + (size_t)B * C * HW;
    unsigned short* rsB = csB + (size_t)B * C * HW;

    const int grid = NCOLB + NROWB;   // 228 + 1824 = 2052

    // A0: f0 = mask -> csA, rsA (+ dcol, drow)
    k_iter<true><<<grid, NTHR, 0, stream>>>(mask, edge, nullptr, nullptr, csA, rsA, dcol, drow);
    // A1: fold A -> B
    k_iter<false><<<grid, NTHR, 0, stream>>>(nullptr, edge, csA, rsA, csB, rsB, dcol, drow);
    // A2: fold B -> A
    k_iter<false><<<grid, NTHR, 0, stream>>>(nullptr, edge, csB, rsB, csA, rsA, dcol, drow);
    // final combine -> out
    k_comb<<<(B * C * HW) / (4 * 256), 256, 0, stream>>>(csA, rsA, dcol, drow, out);
}